// Round 1
// baseline (612.744 us; speedup 1.0000x reference)
//
#include <hip/hip_runtime.h>
#include <hip/hip_bf16.h>
#include <stdint.h>

#define DIMS 1024
#define STATE 2048
#define BATCH 4
#define SEQ 2048
#define TOKENS 8192   // BATCH*SEQ
#define N1 8192       // STATE + 3*STATE columns of fused GEMM1

typedef __hip_bfloat16 bf16;
typedef __attribute__((ext_vector_type(8))) short bf16x8;
typedef __attribute__((ext_vector_type(4))) float f32x4;

__device__ __forceinline__ float sigmoidf_(float x) {
  return 1.0f / (1.0f + __expf(-x));
}

// async global->LDS, 16B per lane. LDS dest must be wave-uniform base; HW does base + lane*16.
__device__ __forceinline__ void async_copy16(const void* g, void* l) {
  __builtin_amdgcn_global_load_lds(
      (const __attribute__((address_space(1))) void*)(uintptr_t)g,
      (__attribute__((address_space(3))) void*)(uint32_t)(uintptr_t)l,
      16, 0, 0);
}

// ---------------- weight transpose + fp32->bf16 cast: W[K][N] -> Wt[N][K] ----------------
__global__ __launch_bounds__(256) void transpose_bf16_kernel(
    const float* __restrict__ W, bf16* __restrict__ Wt, int K, int N) {
  __shared__ float tile[32][33];
  int tx = threadIdx.x & 31;
  int ty = threadIdx.x >> 5;  // 0..7
  long col = (long)blockIdx.x * 32 + tx;
  long rowb = (long)blockIdx.y * 32;
#pragma unroll
  for (int i = 0; i < 32; i += 8)
    tile[ty + i][tx] = W[(rowb + ty + i) * N + col];
  __syncthreads();
  long ocol = rowb + tx;                      // k index
  long orow = (long)blockIdx.x * 32 + ty;     // n index
#pragma unroll
  for (int i = 0; i < 32; i += 8)
    Wt[(orow + i) * K + ocol] = __float2bfloat16(tile[tx][ty + i]);
}

// ---------------- split RMSNorm -> bf16 ----------------
__global__ __launch_bounds__(256) void rmsnorm_kernel(
    const float* __restrict__ x, const float* __restrict__ ls,
    const float* __restrict__ rs, const float* __restrict__ ss,
    bf16* __restrict__ xn) {
  int token = blockIdx.x;
  int tid = threadIdx.x;  // 256 threads, 4 floats each
  const float4* xt = (const float4*)(x + (long)token * DIMS);
  float4 v = xt[tid];
  float s = v.x * v.x + v.y * v.y + v.z * v.z + v.w * v.w;
#pragma unroll
  for (int d = 32; d > 0; d >>= 1) s += __shfl_down(s, d);
  __shared__ float parts[4];
  if ((tid & 63) == 0) parts[tid >> 6] = s;
  __syncthreads();
  int j = tid * 4;
  bool left = j < 512;  // waves 0,1 cover elements 0..511
  float sum = left ? (parts[0] + parts[1]) : (parts[2] + parts[3]);
  float n = sqrtf(sum * (1.0f / 512.0f));  // ||v||*d^-1/2
  float inv = 1.0f / (n + 1e-8f);
  const float4* sc = (const float4*)(left ? ls : rs);
  float4 g = sc[left ? tid : tid - 128];
  float4 p = ((const float4*)ss)[tid];
  bf16* o = xn + (long)token * DIMS + j;
  o[0] = __float2bfloat16(v.x * g.x * inv * p.x);
  o[1] = __float2bfloat16(v.y * g.y * inv * p.y);
  o[2] = __float2bfloat16(v.z * g.z * inv * p.z);
  o[3] = __float2bfloat16(v.w * g.w * inv * p.w);
}

// ---------------- m97-style GEMM: C[M,N] = A[M,K] @ Bt[N,K]^T ----------------
// EPI==0: store bf16 C.  EPI==1: store fp32 C + residual.
template <int EPI>
__global__ __launch_bounds__(256) void gemm_bt(
    const bf16* __restrict__ A, const bf16* __restrict__ Bt,
    void* __restrict__ Cout, const float* __restrict__ resid,
    int M, int N, int K) {
  __shared__ __align__(16) bf16 As[128 * 32];
  __shared__ __align__(16) bf16 Bs[128 * 32];
  int tid = threadIdx.x;
  int lane = tid & 63, wave = tid >> 6;
  int wm = wave & 1, wn = wave >> 1;  // 2x2 wave grid, 64x64 each
  long arow0 = (long)blockIdx.y * 128;
  long brow0 = (long)blockIdx.x * 128;
  int r = lane & 15, q = lane >> 4;
  f32x4 acc[4][4] = {};

  for (int k0 = 0; k0 < K; k0 += 32) {
    __syncthreads();  // previous iter's LDS reads done before overwrite
#pragma unroll
    for (int i = 0; i < 2; i++) {
      int c = (wave * 2 + i) * 64 + lane;  // 16B chunk id, 0..511
      int row = c >> 2;
      int kp = (c & 3) * 8;
      async_copy16(A + (arow0 + row) * K + k0 + kp, (char*)As + (wave * 2 + i) * 1024);
      async_copy16(Bt + (brow0 + row) * K + k0 + kp, (char*)Bs + (wave * 2 + i) * 1024);
    }
    __syncthreads();  // compiler drains vmcnt(0) before barrier -> LDS visible
    const bf16x8* AsV = (const bf16x8*)As;
    const bf16x8* BsV = (const bf16x8*)Bs;
    bf16x8 af[4], bfr[4];
#pragma unroll
    for (int mt = 0; mt < 4; mt++) af[mt] = AsV[(wm * 64 + mt * 16 + r) * 4 + q];
#pragma unroll
    for (int nt = 0; nt < 4; nt++) bfr[nt] = BsV[(wn * 64 + nt * 16 + r) * 4 + q];
#pragma unroll
    for (int mt = 0; mt < 4; mt++)
#pragma unroll
      for (int nt = 0; nt < 4; nt++)
        acc[mt][nt] = __builtin_amdgcn_mfma_f32_16x16x32_bf16(af[mt], bfr[nt], acc[mt][nt], 0, 0, 0);
  }

  // C/D layout: col = lane&15 (=r), row = (lane>>4)*4 + reg (=q*4+reg)  [m89-verified]
  if (EPI == 0) {
    bf16* C = (bf16*)Cout;
#pragma unroll
    for (int mt = 0; mt < 4; mt++)
#pragma unroll
      for (int reg = 0; reg < 4; reg++) {
        long row = arow0 + wm * 64 + mt * 16 + q * 4 + reg;
#pragma unroll
        for (int nt = 0; nt < 4; nt++) {
          long col = brow0 + wn * 64 + nt * 16 + r;
          C[row * N + col] = __float2bfloat16(acc[mt][nt][reg]);
        }
      }
  } else {
    float* C = (float*)Cout;
#pragma unroll
    for (int mt = 0; mt < 4; mt++)
#pragma unroll
      for (int reg = 0; reg < 4; reg++) {
        long row = arow0 + wm * 64 + mt * 16 + q * 4 + reg;
#pragma unroll
        for (int nt = 0; nt < 4; nt++) {
          long col = brow0 + wn * 64 + nt * 16 + r;
          C[row * N + col] = acc[mt][nt][reg] + resid[row * N + col];
        }
      }
  }
}

// ---------------- gated linear scan over time ----------------
// C1: [8192 tokens][8192] bf16 raw GEMM1 out: cols [0,2048)=Kraw, [2048,4096)=u,
// [4096,6144)=g_in, [6144,8192)=g_out.  out: [8192][2048] bf16 = h*sigmoid(g_out).
// Block: 32 channels x full sequence for one batch. Wave-scan along time (lane=time).
__global__ __launch_bounds__(256) void scan_kernel(
    const bf16* __restrict__ C1, bf16* __restrict__ out) {
  int b = blockIdx.x;              // batch 0..3
  int c0 = blockIdx.y * 32;        // channel base
  __shared__ float a_s[32][65], u_s[32][65], g_s[32][65], h_s[32][65];
  int tid = threadIdx.x;
  int lane = tid & 63, wave = tid >> 6;
  int cc = tid & 31;   // channel within tile (load/store phases)
  int tq = tid >> 5;   // 0..7

  float carryH[8], carryK[8];
#pragma unroll
  for (int i = 0; i < 8; i++) { carryH[i] = 0.0f; carryK[i] = 1.0f; }

  for (int t0 = 0; t0 < SEQ; t0 += 64) {
    // load + gate: lanes along channels (coalesced 64B rows)
#pragma unroll
    for (int i = 0; i < 8; i++) {
      int t = tq * 8 + i;
      long rowoff = ((long)(b * SEQ + t0 + t)) * N1 + c0 + cc;
      float kraw = __bfloat162float(C1[rowoff]);
      float uraw = __bfloat162float(C1[rowoff + 2048]);
      float gin  = __bfloat162float(C1[rowoff + 4096]);
      float gout = __bfloat162float(C1[rowoff + 6144]);
      float aK = sigmoidf_(kraw);
      a_s[cc][t] = aK;
      u_s[cc][t] = uraw * sigmoidf_(gin) * (1.0f - aK);
      g_s[cc][t] = sigmoidf_(gout);
    }
    __syncthreads();
    // scan: each wave owns 8 channels; lane = time
#pragma unroll
    for (int i = 0; i < 8; i++) {
      int ch = wave * 8 + i;
      float aK = a_s[ch][lane];
      float u = u_s[ch][lane];
      float a = __shfl_up(aK, 1);     // a_t = K_{t-1}
      if (lane == 0) a = carryK[i];
      float A = a, U = u;
#pragma unroll
      for (int d = 1; d < 64; d <<= 1) {
        float Au = __shfl_up(A, d);
        float Uu = __shfl_up(U, d);
        if (lane >= d) { U += A * Uu; A *= Au; }
      }
      float h = U + A * carryH[i];
      carryH[i] = __shfl(h, 63);
      carryK[i] = __shfl(aK, 63);
      h_s[ch][lane] = h * g_s[ch][lane];
    }
    __syncthreads();
    // store: lanes along channels (coalesced)
#pragma unroll
    for (int i = 0; i < 8; i++) {
      int t = tq * 8 + i;
      out[((long)(b * SEQ + t0 + t)) * STATE + c0 + cc] = __float2bfloat16(h_s[cc][t]);
    }
    __syncthreads();  // h_s consumed before next iter overwrites
  }
}

extern "C" void kernel_launch(void* const* d_in, const int* in_sizes, int n_in,
                              void* d_out, int out_size, void* d_ws, size_t ws_size,
                              hipStream_t stream) {
  const float* x    = (const float*)d_in[0];
  const float* ls   = (const float*)d_in[1];
  const float* rs   = (const float*)d_in[2];
  const float* ss   = (const float*)d_in[3];
  const float* Wk   = (const float*)d_in[4];
  const float* Wugg = (const float*)d_in[5];
  const float* Wout = (const float*)d_in[6];
  float* out = (float*)d_out;

  // workspace layout (196 MB total)
  char* ws = (char*)d_ws;
  bf16* W1t = (bf16*)ws;                                   // [8192][1024] = Wk^T | Wugg^T
  bf16* W2t = (bf16*)(ws + 16777216);                      // [1024][2048] = Wout^T
  bf16* xn  = (bf16*)(ws + 16777216 + 4194304);            // [8192][1024]
  bf16* C1  = (bf16*)(ws + 16777216 + 4194304 + 16777216); // [8192][8192]
  bf16* sco = (bf16*)(ws + 16777216 + 4194304 + 16777216 + 134217728); // [8192][2048]

  // weights -> bf16, transposed to [N][K]
  transpose_bf16_kernel<<<dim3(STATE / 32, DIMS / 32), 256, 0, stream>>>(Wk, W1t, DIMS, STATE);
  transpose_bf16_kernel<<<dim3(3 * STATE / 32, DIMS / 32), 256, 0, stream>>>(
      Wugg, W1t + (long)STATE * DIMS, DIMS, 3 * STATE);
  transpose_bf16_kernel<<<dim3(DIMS / 32, STATE / 32), 256, 0, stream>>>(Wout, W2t, STATE, DIMS);

  rmsnorm_kernel<<<TOKENS, 256, 0, stream>>>(x, ls, rs, ss, xn);

  gemm_bt<0><<<dim3(N1 / 128, TOKENS / 128), 256, 0, stream>>>(
      xn, W1t, (void*)C1, nullptr, TOKENS, N1, DIMS);

  scan_kernel<<<dim3(BATCH, STATE / 32), 256, 0, stream>>>(C1, sco);

  gemm_bt<1><<<dim3(DIMS / 128, TOKENS / 128), 256, 0, stream>>>(
      sco, W2t, (void*)out, x, TOKENS, DIMS, STATE);
}

// Round 2
// 467.628 us; speedup vs baseline: 1.3103x; 1.3103x over previous
//
#include <hip/hip_runtime.h>
#include <hip/hip_bf16.h>
#include <stdint.h>

#define DIMS 1024
#define STATE 2048
#define BATCH 4
#define SEQ 2048
#define TOKENS 8192   // BATCH*SEQ
#define N1 8192       // STATE + 3*STATE columns of fused GEMM1
#define NCHUNK 16
#define CHUNKL (SEQ / NCHUNK)   // 128

typedef __hip_bfloat16 bf16;
typedef __attribute__((ext_vector_type(8))) short bf16x8;
typedef __attribute__((ext_vector_type(4))) float f32x4;

__device__ __forceinline__ float sigmoidf_(float x) {
  return 1.0f / (1.0f + __expf(-x));
}

// async global->LDS, 16B per lane. LDS dest must be wave-uniform base; HW does base + lane*16.
__device__ __forceinline__ void async_copy16(const void* g, void* l) {
  __builtin_amdgcn_global_load_lds(
      (const __attribute__((address_space(1))) void*)(uintptr_t)g,
      (__attribute__((address_space(3))) void*)(uint32_t)(uintptr_t)l,
      16, 0, 0);
}

// ---------------- weight transpose + fp32->bf16 cast: W[K][N] -> Wt[N][K] ----------------
__global__ __launch_bounds__(256) void transpose_bf16_kernel(
    const float* __restrict__ W, bf16* __restrict__ Wt, int K, int N) {
  __shared__ float tile[32][33];
  int tx = threadIdx.x & 31;
  int ty = threadIdx.x >> 5;  // 0..7
  long col = (long)blockIdx.x * 32 + tx;
  long rowb = (long)blockIdx.y * 32;
#pragma unroll
  for (int i = 0; i < 32; i += 8)
    tile[ty + i][tx] = W[(rowb + ty + i) * N + col];
  __syncthreads();
  long ocol = rowb + tx;                      // k index
  long orow = (long)blockIdx.x * 32 + ty;     // n index
#pragma unroll
  for (int i = 0; i < 32; i += 8)
    Wt[(orow + i) * K + ocol] = __float2bfloat16(tile[tx][ty + i]);
}

// ---------------- split RMSNorm -> bf16 ----------------
__global__ __launch_bounds__(256) void rmsnorm_kernel(
    const float* __restrict__ x, const float* __restrict__ ls,
    const float* __restrict__ rs, const float* __restrict__ ss,
    bf16* __restrict__ xn) {
  int token = blockIdx.x;
  int tid = threadIdx.x;  // 256 threads, 4 floats each
  const float4* xt = (const float4*)(x + (long)token * DIMS);
  float4 v = xt[tid];
  float s = v.x * v.x + v.y * v.y + v.z * v.z + v.w * v.w;
#pragma unroll
  for (int d = 32; d > 0; d >>= 1) s += __shfl_down(s, d);
  __shared__ float parts[4];
  if ((tid & 63) == 0) parts[tid >> 6] = s;
  __syncthreads();
  int j = tid * 4;
  bool left = j < 512;  // waves 0,1 cover elements 0..511
  float sum = left ? (parts[0] + parts[1]) : (parts[2] + parts[3]);
  float n = sqrtf(sum * (1.0f / 512.0f));  // ||v||*d^-1/2
  float inv = 1.0f / (n + 1e-8f);
  const float4* sc = (const float4*)(left ? ls : rs);
  float4 g = sc[left ? tid : tid - 128];
  float4 p = ((const float4*)ss)[tid];
  bf16* o = xn + (long)token * DIMS + j;
  o[0] = __float2bfloat16(v.x * g.x * inv * p.x);
  o[1] = __float2bfloat16(v.y * g.y * inv * p.y);
  o[2] = __float2bfloat16(v.z * g.z * inv * p.z);
  o[3] = __float2bfloat16(v.w * g.w * inv * p.w);
}

// ---------------- m97-style GEMM: C[M,N] = A[M,K] @ Bt[N,K]^T ----------------
// EPI==0: store bf16 C.  EPI==1: store fp32 C + residual.
template <int EPI>
__global__ __launch_bounds__(256) void gemm_bt(
    const bf16* __restrict__ A, const bf16* __restrict__ Bt,
    void* __restrict__ Cout, const float* __restrict__ resid,
    int M, int N, int K) {
  __shared__ __align__(16) bf16 As[128 * 32];
  __shared__ __align__(16) bf16 Bs[128 * 32];
  int tid = threadIdx.x;
  int lane = tid & 63, wave = tid >> 6;
  int wm = wave & 1, wn = wave >> 1;  // 2x2 wave grid, 64x64 each
  long arow0 = (long)blockIdx.y * 128;
  long brow0 = (long)blockIdx.x * 128;
  int r = lane & 15, q = lane >> 4;
  f32x4 acc[4][4] = {};

  for (int k0 = 0; k0 < K; k0 += 32) {
    __syncthreads();  // previous iter's LDS reads done before overwrite
#pragma unroll
    for (int i = 0; i < 2; i++) {
      int c = (wave * 2 + i) * 64 + lane;  // 16B chunk id, 0..511
      int row = c >> 2;
      int kp = (c & 3) * 8;
      async_copy16(A + (arow0 + row) * K + k0 + kp, (char*)As + (wave * 2 + i) * 1024);
      async_copy16(Bt + (brow0 + row) * K + k0 + kp, (char*)Bs + (wave * 2 + i) * 1024);
    }
    __syncthreads();  // compiler drains vmcnt(0) before barrier -> LDS visible
    const bf16x8* AsV = (const bf16x8*)As;
    const bf16x8* BsV = (const bf16x8*)Bs;
    bf16x8 af[4], bfr[4];
#pragma unroll
    for (int mt = 0; mt < 4; mt++) af[mt] = AsV[(wm * 64 + mt * 16 + r) * 4 + q];
#pragma unroll
    for (int nt = 0; nt < 4; nt++) bfr[nt] = BsV[(wn * 64 + nt * 16 + r) * 4 + q];
#pragma unroll
    for (int mt = 0; mt < 4; mt++)
#pragma unroll
      for (int nt = 0; nt < 4; nt++)
        acc[mt][nt] = __builtin_amdgcn_mfma_f32_16x16x32_bf16(af[mt], bfr[nt], acc[mt][nt], 0, 0, 0);
  }

  // C/D layout: col = lane&15 (=r), row = (lane>>4)*4 + reg (=q*4+reg)  [m89-verified]
  if (EPI == 0) {
    bf16* C = (bf16*)Cout;
#pragma unroll
    for (int mt = 0; mt < 4; mt++)
#pragma unroll
      for (int reg = 0; reg < 4; reg++) {
        long row = arow0 + wm * 64 + mt * 16 + q * 4 + reg;
#pragma unroll
        for (int nt = 0; nt < 4; nt++) {
          long col = brow0 + wn * 64 + nt * 16 + r;
          C[row * N + col] = __float2bfloat16(acc[mt][nt][reg]);
        }
      }
  } else {
    float* C = (float*)Cout;
#pragma unroll
    for (int mt = 0; mt < 4; mt++)
#pragma unroll
      for (int reg = 0; reg < 4; reg++) {
        long row = arow0 + wm * 64 + mt * 16 + q * 4 + reg;
#pragma unroll
        for (int nt = 0; nt < 4; nt++) {
          long col = brow0 + wn * 64 + nt * 16 + r;
          C[row * N + col] = acc[mt][nt][reg] + resid[row * N + col];
        }
      }
  }
}

// ---------------- chunked gated linear scan ----------------
// Recurrence: h_t = a_t*h_{t-1} + u_t, a_t = sigmoid(Kraw_{t-1}) (a_0=1),
// u_t = uraw_t*sigmoid(gin_t)*(1-sigmoid(Kraw_t)).  Over a chunk this composes
// to h_out = A*h_in + U, enabling a 3-pass parallel scan over NCHUNK chunks.

// Pass A: per (batch, channel, chunk) thread reduces the chunk to (A, U).
// Reads K/u/g_in streams only. Coalesced across channels.
__global__ __launch_bounds__(256) void chunk_summary_kernel(
    const bf16* __restrict__ C1, float* __restrict__ carryA,
    float* __restrict__ carryU) {
  int b = blockIdx.x;
  int ch = blockIdx.y * 256 + threadIdx.x;
  int chunk = blockIdx.z;
  int t0 = chunk * CHUNKL;
  long base = ((long)b * SEQ) * N1 + ch;
  float kp = 0.0f;
  if (chunk != 0) kp = __bfloat162float(C1[base + (long)(t0 - 1) * N1]);
  float a_first = (chunk == 0) ? 1.0f : sigmoidf_(kp);
  float A = 1.0f, U = 0.0f;
#pragma unroll 8
  for (int t = t0; t < t0 + CHUNKL; t++) {
    long off = base + (long)t * N1;
    float kraw = __bfloat162float(C1[off]);
    float uraw = __bfloat162float(C1[off + 2048]);
    float gin  = __bfloat162float(C1[off + 4096]);
    float a = (t == t0) ? a_first : sigmoidf_(kp);
    float sK = sigmoidf_(kraw);
    float u = uraw * sigmoidf_(gin) * (1.0f - sK);
    A *= a;
    U = a * U + u;
    kp = kraw;
  }
  int cidx = (b * NCHUNK + chunk) * STATE + ch;
  carryA[cidx] = A;
  carryU[cidx] = U;
}

// Pass B: exclusive scan of chunk carries along the chunk axis per channel.
__global__ __launch_bounds__(256) void carry_scan_kernel(
    const float* __restrict__ carryA, const float* __restrict__ carryU,
    float* __restrict__ carryIn) {
  int idx = blockIdx.x * 256 + threadIdx.x;  // b*STATE + ch
  int b = idx >> 11;
  int ch = idx & 2047;
  float h = 0.0f;
#pragma unroll
  for (int c = 0; c < NCHUNK; c++) {
    int cidx = (b * NCHUNK + c) * STATE + ch;
    carryIn[cidx] = h;
    h = carryA[cidx] * h + carryU[cidx];
  }
}

// Pass C: per-chunk local scan seeded with carryIn; writes h*sigmoid(g_out).
// Block: 32 channels x one chunk (2 time-tiles of 64). Wave-scan, lane=time.
__global__ __launch_bounds__(256) void scan_chunk_kernel(
    const bf16* __restrict__ C1, const float* __restrict__ carryIn,
    bf16* __restrict__ out) {
  int b = blockIdx.x;              // batch 0..3
  int c0 = blockIdx.y * 32;        // channel base
  int chunk = blockIdx.z;
  int tstart = chunk * CHUNKL;
  __shared__ float a_s[32][65], u_s[32][65], h_s[32][65];
  int tid = threadIdx.x;
  int lane = tid & 63, wave = tid >> 6;
  int cc = tid & 31;   // channel within tile (load/store phases)
  int tq = tid >> 5;   // 0..7

  float carryH[8], carryK[8];
#pragma unroll
  for (int i = 0; i < 8; i++) {
    int ch = c0 + wave * 8 + i;
    carryH[i] = carryIn[(b * NCHUNK + chunk) * STATE + ch];
    carryK[i] = (chunk == 0)
                    ? 1.0f
                    : sigmoidf_(__bfloat162float(
                          C1[((long)(b * SEQ + tstart - 1)) * N1 + ch]));
  }

  float g_r[8];
  for (int t0 = tstart; t0 < tstart + CHUNKL; t0 += 64) {
    // load + gate: lanes along channels (coalesced rows); g_out stays in regs
#pragma unroll
    for (int i = 0; i < 8; i++) {
      int t = tq * 8 + i;
      long rowoff = ((long)(b * SEQ + t0 + t)) * N1 + c0 + cc;
      float kraw = __bfloat162float(C1[rowoff]);
      float uraw = __bfloat162float(C1[rowoff + 2048]);
      float gin  = __bfloat162float(C1[rowoff + 4096]);
      float gout = __bfloat162float(C1[rowoff + 6144]);
      float aK = sigmoidf_(kraw);
      a_s[cc][t] = aK;
      u_s[cc][t] = uraw * sigmoidf_(gin) * (1.0f - aK);
      g_r[i] = sigmoidf_(gout);
    }
    __syncthreads();
    // scan: each wave owns 8 channels; lane = time
#pragma unroll
    for (int i = 0; i < 8; i++) {
      int ch = wave * 8 + i;
      float aK = a_s[ch][lane];
      float u = u_s[ch][lane];
      float a = __shfl_up(aK, 1);     // a_t = K_{t-1}
      if (lane == 0) a = carryK[i];
      float A = a, U = u;
#pragma unroll
      for (int d = 1; d < 64; d <<= 1) {
        float Au = __shfl_up(A, d);
        float Uu = __shfl_up(U, d);
        if (lane >= d) { U += A * Uu; A *= Au; }
      }
      float h = U + A * carryH[i];
      carryH[i] = __shfl(h, 63);
      carryK[i] = __shfl(aK, 63);
      h_s[ch][lane] = h;
    }
    __syncthreads();
    // store: lanes along channels (coalesced); apply register-held g_out
#pragma unroll
    for (int i = 0; i < 8; i++) {
      int t = tq * 8 + i;
      out[((long)(b * SEQ + t0 + t)) * STATE + c0 + cc] =
          __float2bfloat16(h_s[cc][t] * g_r[i]);
    }
    __syncthreads();  // h_s consumed before next iter overwrites
  }
}

extern "C" void kernel_launch(void* const* d_in, const int* in_sizes, int n_in,
                              void* d_out, int out_size, void* d_ws, size_t ws_size,
                              hipStream_t stream) {
  const float* x    = (const float*)d_in[0];
  const float* ls   = (const float*)d_in[1];
  const float* rs   = (const float*)d_in[2];
  const float* ss   = (const float*)d_in[3];
  const float* Wk   = (const float*)d_in[4];
  const float* Wugg = (const float*)d_in[5];
  const float* Wout = (const float*)d_in[6];
  float* out = (float*)d_out;

  // workspace layout (~205.5 MB total)
  char* ws = (char*)d_ws;
  bf16* W1t = (bf16*)ws;                                   // [8192][1024] = Wk^T | Wugg^T
  bf16* W2t = (bf16*)(ws + 16777216);                      // [1024][2048] = Wout^T
  bf16* xn  = (bf16*)(ws + 16777216 + 4194304);            // [8192][1024]
  bf16* C1  = (bf16*)(ws + 16777216 + 4194304 + 16777216); // [8192][8192]
  bf16* sco = (bf16*)(ws + 16777216 + 4194304 + 16777216 + 134217728); // [8192][2048]
  // carry buffers (3 x 512 KB) overlay the xn region: xn is dead after GEMM1,
  // and the scan passes run strictly after GEMM1 in stream order.
  float* carryA  = (float*)xn;
  float* carryU  = carryA + BATCH * NCHUNK * STATE;
  float* carryIn = carryU + BATCH * NCHUNK * STATE;

  // weights -> bf16, transposed to [N][K]
  transpose_bf16_kernel<<<dim3(STATE / 32, DIMS / 32), 256, 0, stream>>>(Wk, W1t, DIMS, STATE);
  transpose_bf16_kernel<<<dim3(3 * STATE / 32, DIMS / 32), 256, 0, stream>>>(
      Wugg, W1t + (long)STATE * DIMS, DIMS, 3 * STATE);
  transpose_bf16_kernel<<<dim3(DIMS / 32, STATE / 32), 256, 0, stream>>>(Wout, W2t, STATE, DIMS);

  rmsnorm_kernel<<<TOKENS, 256, 0, stream>>>(x, ls, rs, ss, xn);

  gemm_bt<0><<<dim3(N1 / 128, TOKENS / 128), 256, 0, stream>>>(
      xn, W1t, (void*)C1, nullptr, TOKENS, N1, DIMS);

  chunk_summary_kernel<<<dim3(BATCH, STATE / 256, NCHUNK), 256, 0, stream>>>(
      C1, carryA, carryU);
  carry_scan_kernel<<<dim3(BATCH * STATE / 256), 256, 0, stream>>>(
      carryA, carryU, carryIn);
  scan_chunk_kernel<<<dim3(BATCH, STATE / 32, NCHUNK), 256, 0, stream>>>(
      C1, carryIn, sco);

  gemm_bt<1><<<dim3(DIMS / 128, TOKENS / 128), 256, 0, stream>>>(
      sco, W2t, (void*)out, x, TOKENS, DIMS, STATE);
}